// Round 6
// baseline (291.604 us; speedup 1.0000x reference)
//
#include <hip/hip_runtime.h>
#include <hip/hip_cooperative_groups.h>

namespace cg = cooperative_groups;

typedef unsigned short USH;
typedef unsigned int   UIN;
typedef unsigned char  UCH;

static constexpr int Bn = 1024;    // batch
static constexpr int Hn = 200;     // history length
static constexpr int Dn = 128;     // embed/hidden
static constexpr int Dh = 64;      // half embed
static constexpr int NITEM = 50000;
static constexpr int NREG  = 1000;
static constexpr int MT = 64;      // items per ab block
static constexpr int AB_A_BLOCKS = (NITEM + MT - 1) / MT;  // 782
static constexpr int AB_B_BLOCKS = (NREG  + MT - 1) / MT;  // 16
static constexpr int AB_TOT = AB_A_BLOCKS + AB_B_BLOCKS;   // 798
static constexpr int QU_BLOCKS = Bn / 4;                   // 256 (4 rows/block)
static constexpr int G_BLOCKS  = Bn / 16;                  // 64  (16 rows/block)
static constexpr int WTS = 132;    // wt stride (floats)
static constexpr int ETS = 69;     // et stride (floats)
static constexpr int CR  = 50;     // kv rows per chunk (32*200 == 50*128)
static constexpr int RS  = 192;    // fused fp8 row stride: 128 proj + 64 raw
static constexpr int VIRT_A = AB_TOT + QU_BLOCKS + G_BLOCKS;  // 1118

// fp8 tables scaled by FSCALE before encode; consumers fold in 1/FSCALE.
static constexpr float FSCALE = 128.f;
static constexpr float FINV   = 1.f / 128.f;

__device__ __forceinline__ float bf2f(USH u) {
  return __uint_as_float(((UIN)u) << 16);
}
__device__ __forceinline__ USH f2b(float f) {  // fp32 -> bf16 rne
  UIN x = __float_as_uint(f);
  return (USH)((x + 0x7fffu + ((x >> 16) & 1u)) >> 16);
}
__device__ __forceinline__ UIN enc4(float a, float b, float c, float d) {
  // 4 fp32 -> 4 fp8 e4m3 packed in one dword (hw cvt, RNE+sat)
  int w = __builtin_amdgcn_cvt_pk_fp8_f32(a, b, 0, false);
  w = __builtin_amdgcn_cvt_pk_fp8_f32(c, d, w, true);
  return (UIN)w;
}
__device__ __forceinline__ void dec4(UIN w, float* o) {  // 4 fp8 -> 4 fp32
  auto lo = __builtin_amdgcn_cvt_pk_f32_fp8((int)w, false);
  auto hi = __builtin_amdgcn_cvt_pk_f32_fp8((int)w, true);
  o[0] = lo[0]; o[1] = lo[1]; o[2] = hi[0]; o[3] = hi[1];
}

// ---------------------------------------------------------------------------
// v16: single cooperative kernel = [phase A: tables/qv/uv/g] grid.sync
//      [phase B: scores+s1/s2] grid.sync [phase C: epilogue].
// Bodies identical to v15; LDS is a 51456B union (3 blocks/CU).
// Purpose: (1) expose our GPU time as one >42us dispatch with counters,
// (2) remove inter-kernel launch gaps.
// ---------------------------------------------------------------------------
__global__ __launch_bounds__(256, 3) void mega_kernel(
    const int* __restrict__ history, const int* __restrict__ target,
    const int* __restrict__ hregion, const int* __restrict__ tregion,
    const float* __restrict__ hv, const float* __restrict__ dist_mat,
    const int* __restrict__ uid,
    const float* __restrict__ Et, const float* __restrict__ Er,
    const float* __restrict__ embed_dist,
    const float* __restrict__ Wq, const float* __restrict__ Wk,
    const float* __restrict__ Wv,
    UCH* __restrict__ Cf, UCH* __restrict__ Df,
    float* __restrict__ qvt, float* __restrict__ uvt, float* __restrict__ g,
    float* __restrict__ psc, float2* __restrict__ s12,
    float* __restrict__ out) {
  __shared__ float smem[64 * WTS + 64 * ETS];   // 51456 B -> 3 blocks/CU
  int tid = threadIdx.x;
  cg::grid_group grid = cg::this_grid();

  // ===================== Phase A: tables + qv/uv + g =====================
  {
    float* wt = smem;
    float* et = smem + 64 * WTS;
    for (int blk = blockIdx.x; blk < VIRT_A; blk += gridDim.x) {
      __syncthreads();   // protect LDS reuse across virtual blocks
      if (blk >= AB_TOT + QU_BLOCKS) {
        // -------- g-accumulate path (64 vblocks x 16 rows) --------
        int c = tid;
        const float* row = embed_dist + (size_t)uid[0] * NREG;  // 4KB, L1
        float acc = 0.f;
        int ibase = (blk - AB_TOT - QU_BLOCKS) * 16;
        for (int ii = 0; ii < 16; ii++) {
          int i = ibase + ii;
          float td = row[tregion[i]];             // wave-uniform broadcast
          if (c < Hn) acc += td * row[hregion[(size_t)i * Hn + c]];
        }
        if (c < Hn) atomicAdd(&g[c], acc);
      } else if (blk >= AB_TOT) {
        // -------- qv/uv precompute path --------
        float* te = wt;  // te[ii*128 + d], 4 target-embed rows
        int i0 = (blk - AB_TOT) * 4;
#pragma unroll
        for (int v = 0; v < 2; v++) {
          int idx = v * 256 + tid;      // 0..511
          int ii = idx >> 7, d = idx & 127;
          int it = i0 + ii;
          te[ii * 128 + d] = (d < 64) ? Et[(size_t)target[it] * Dh + d]
                                      : Er[(size_t)tregion[it] * Dh + (d - 64)];
        }
        __syncthreads();
        int j = tid & 127, half = tid >> 7;
        float a0 = 0.f, a1 = 0.f, a2 = 0.f, a3 = 0.f;
        if (half == 0) {  // qv: thread j owns Wq row j, 4 batch rows at once
          const float* wr = Wq + (size_t)j * Dn;
#pragma unroll 8
          for (int k = 0; k < 128; k++) {
            float w = wr[k];
            a0 += w * te[k]; a1 += w * te[128 + k];
            a2 += w * te[256 + k]; a3 += w * te[384 + k];
          }
          const float s = 0.088388347648318447f;  // 1/sqrt(128)
          qvt[(size_t)(i0 + 0) * Dn + j] = a0 * s;
          qvt[(size_t)(i0 + 1) * Dn + j] = a1 * s;
          qvt[(size_t)(i0 + 2) * Dn + j] = a2 * s;
          qvt[(size_t)(i0 + 3) * Dn + j] = a3 * s;
        } else {          // uv: column sweep, coalesced across d
          int d = j;
#pragma unroll 8
          for (int k = 0; k < 128; k++) {
            float w = Wv[(size_t)k * Dn + d];
            a0 += w * te[k]; a1 += w * te[128 + k];
            a2 += w * te[256 + k]; a3 += w * te[384 + k];
          }
          uvt[(size_t)(i0 + 0) * Dn + d] = a0;
          uvt[(size_t)(i0 + 1) * Dn + d] = a1;
          uvt[(size_t)(i0 + 2) * Dn + d] = a2;
          uvt[(size_t)(i0 + 3) * Dn + d] = a3;
        }
      } else {
        // -------- fused-table GEMM path --------
        const float* E; UCH* OutT; int nmax, base, koff;
        if (blk < AB_A_BLOCKS) { E = Et; OutT = Cf; nmax = NITEM; base = blk * MT; koff = 0; }
        else { E = Er; OutT = Df; nmax = NREG; base = (blk - AB_A_BLOCKS) * MT; koff = 64; }

        // stage Wk transposed
#pragma unroll
        for (int p = 0; p < 8; p++) {
          int idx = p * 256 + tid;
          int row = idx >> 4, c4 = idx & 15;
          float4 w = *reinterpret_cast<const float4*>(Wk + (size_t)row * Dn + koff + c4 * 4);
          wt[(c4 * 4 + 0) * WTS + row] = w.x;
          wt[(c4 * 4 + 1) * WTS + row] = w.y;
          wt[(c4 * 4 + 2) * WTS + row] = w.z;
          wt[(c4 * 4 + 3) * WTS + row] = w.w;
        }
        // stage E rows row-major
#pragma unroll
        for (int p = 0; p < 4; p++) {
          int idx = p * 256 + tid;
          int m = idx >> 4, c4 = idx & 15;
          int gi = base + m;
          float4 e = make_float4(0.f, 0.f, 0.f, 0.f);
          if (gi < nmax) e = *reinterpret_cast<const float4*>(E + (size_t)gi * Dh + c4 * 4);
          et[m * ETS + c4 * 4 + 0] = e.x;
          et[m * ETS + c4 * 4 + 1] = e.y;
          et[m * ETS + c4 * 4 + 2] = e.z;
          et[m * ETS + c4 * 4 + 3] = e.w;
        }
        __syncthreads();

        // raw-half emit: Cf[item][128 + 4wr..] = fp8(FSCALE * E row)
#pragma unroll
        for (int p = 0; p < 4; p++) {
          int idx = p * 256 + tid;       // 0..1023
          int m = idx >> 4, wr = idx & 15;
          int gi = base + m;
          if (gi < nmax) {
            const float* er = &et[m * ETS + wr * 4];
            *reinterpret_cast<UIN*>(OutT + (size_t)gi * RS + 128 + wr * 4) =
                enc4(er[0] * FSCALE, er[1] * FSCALE, er[2] * FSCALE, er[3] * FSCALE);
          }
        }

        int jt = tid & 15, it = tid >> 4;     // 8 j's, 4 items per thread
        const float* wb = wt + jt * 8;
        const float* eb = et + (it * 4) * ETS;
        float c[4][8];
#pragma unroll
        for (int ii = 0; ii < 4; ii++)
#pragma unroll
          for (int jj = 0; jj < 8; jj++) c[ii][jj] = 0.f;

#pragma unroll 2
        for (int k = 0; k < 64; k++) {
          float4 w0 = *reinterpret_cast<const float4*>(wb + (size_t)k * WTS);
          float4 w1 = *reinterpret_cast<const float4*>(wb + (size_t)k * WTS + 4);
          float e0 = eb[k], e1 = eb[ETS + k], e2 = eb[2 * ETS + k], e3 = eb[3 * ETS + k];
          c[0][0] += e0 * w0.x; c[0][1] += e0 * w0.y; c[0][2] += e0 * w0.z; c[0][3] += e0 * w0.w;
          c[0][4] += e0 * w1.x; c[0][5] += e0 * w1.y; c[0][6] += e0 * w1.z; c[0][7] += e0 * w1.w;
          c[1][0] += e1 * w0.x; c[1][1] += e1 * w0.y; c[1][2] += e1 * w0.z; c[1][3] += e1 * w0.w;
          c[1][4] += e1 * w1.x; c[1][5] += e1 * w1.y; c[1][6] += e1 * w1.z; c[1][7] += e1 * w1.w;
          c[2][0] += e2 * w0.x; c[2][1] += e2 * w0.y; c[2][2] += e2 * w0.z; c[2][3] += e2 * w0.w;
          c[2][4] += e2 * w1.x; c[2][5] += e2 * w1.y; c[2][6] += e2 * w1.z; c[2][7] += e2 * w1.w;
          c[3][0] += e3 * w0.x; c[3][1] += e3 * w0.y; c[3][2] += e3 * w0.z; c[3][3] += e3 * w0.w;
          c[3][4] += e3 * w1.x; c[3][5] += e3 * w1.y; c[3][6] += e3 * w1.z; c[3][7] += e3 * w1.w;
        }

#pragma unroll
        for (int ii = 0; ii < 4; ii++) {
          int item = base + it * 4 + ii;
          if (item < nmax) {
            uint2 pk;
            pk.x = enc4(c[ii][0] * FSCALE, c[ii][1] * FSCALE, c[ii][2] * FSCALE, c[ii][3] * FSCALE);
            pk.y = enc4(c[ii][4] * FSCALE, c[ii][5] * FSCALE, c[ii][6] * FSCALE, c[ii][7] * FSCALE);
            *reinterpret_cast<uint2*>(OutT + (size_t)item * RS + jt * 8) = pk;
          }
        }
      }
    }
  }
  grid.sync();

  // ===================== Phase B: scores + s1/s2 =====================
  {
    USH*   kvs  = (USH*)smem;                 // 12800B = 3200 floats
    uint4* rawA = (uint4*)(smem + 3200);      // 3200B  = 800 floats
    uint4* rawB = (uint4*)(smem + 4000);      // 3200B
    float* tgtE = smem + 4800;
    float* uvf  = smem + 4928;
    float* qv   = smem + 5056;                // +32 -> 5088 total, fits
    for (int vb = blockIdx.x; vb < Bn * 4; vb += gridDim.x) {
      __syncthreads();   // protect LDS reuse across virtual blocks
      int i = vb >> 2, h = vb & 3;
      const int* hrow = history + (size_t)i * Hn + CR * h;
      const int* rrow = hregion + (size_t)i * Hn + CR * h;

      if (tid < 128) {
        tgtE[tid] = FINV * ((tid < 64) ? Et[(size_t)target[i] * Dh + tid]
                                       : Er[(size_t)tregion[i] * Dh + (tid - 64)]);
      } else {
        uvf[tid - 128] = FINV * uvt[(size_t)i * Dn + (tid - 128)];
      }
      if (tid < 32) qv[tid] = FINV * qvt[(size_t)i * Dn + 32 * h + tid];

      // raw staging: 4 lanes x 16B per row (200 active threads)
      {
        int seg = tid & 3, row = tid >> 2;
        if (row < CR) {
          int ia = hrow[row], ib = rrow[row];
          rawA[row * 4 + seg] = *reinterpret_cast<const uint4*>(Cf + (size_t)ia * RS + 128 + seg * 16);
          rawB[row * 4 + seg] = *reinterpret_cast<const uint4*>(Df + (size_t)ib * RS + 128 + seg * 16);
        }
      }

      // proj staging: 8 lanes x 16B per row; decode fp8, add, pack bf16
#pragma unroll
      for (int p = 0; p < 2; p++) {
        int idx = p * 256 + tid;
        int seg = idx & 7, row = idx >> 3;
        if (row < CR) {
          int ia = hrow[row], ib = rrow[row];
          uint4 av = *reinterpret_cast<const uint4*>(Cf + (size_t)ia * RS + seg * 16);
          uint4 bv = *reinterpret_cast<const uint4*>(Df + (size_t)ib * RS + seg * 16);
          float fa[16], fb[16];
          dec4(av.x, fa);      dec4(av.y, fa + 4);  dec4(av.z, fa + 8);  dec4(av.w, fa + 12);
          dec4(bv.x, fb);      dec4(bv.y, fb + 4);  dec4(bv.z, fb + 8);  dec4(bv.w, fb + 12);
          uint4 k0, k1;
          k0.x = (UIN)f2b(fa[0] + fb[0])  | ((UIN)f2b(fa[1] + fb[1]) << 16);
          k0.y = (UIN)f2b(fa[2] + fb[2])  | ((UIN)f2b(fa[3] + fb[3]) << 16);
          k0.z = (UIN)f2b(fa[4] + fb[4])  | ((UIN)f2b(fa[5] + fb[5]) << 16);
          k0.w = (UIN)f2b(fa[6] + fb[6])  | ((UIN)f2b(fa[7] + fb[7]) << 16);
          k1.x = (UIN)f2b(fa[8] + fb[8])  | ((UIN)f2b(fa[9] + fb[9]) << 16);
          k1.y = (UIN)f2b(fa[10] + fb[10]) | ((UIN)f2b(fa[11] + fb[11]) << 16);
          k1.z = (UIN)f2b(fa[12] + fb[12]) | ((UIN)f2b(fa[13] + fb[13]) << 16);
          k1.w = (UIN)f2b(fa[14] + fb[14]) | ((UIN)f2b(fa[15] + fb[15]) << 16);
          *reinterpret_cast<uint4*>(&kvs[row * Dn + seg * 16]) = k0;
          *reinterpret_cast<uint4*>(&kvs[row * Dn + seg * 16 + 8]) = k1;
        }
      }
      __syncthreads();  // kvs + raw + tgtE/uvf/qv ready

      // s1/s2 dots from LDS raw fp8
      int l8 = tid & 7, r8 = tid >> 3;     // 8 lanes/row; rows r8 and 32+r8
#pragma unroll
      for (int pass = 0; pass < 2; pass++) {
        int t = (pass == 0) ? r8 : 32 + r8;
        if (t < CR) {
          uint2 e = *(reinterpret_cast<const uint2*>(&rawA[t * 4]) + l8);
          uint2 r = *(reinterpret_cast<const uint2*>(&rawB[t * 4]) + l8);
          float fe[8], fr[8];
          dec4(e.x, fe); dec4(e.y, fe + 4);
          dec4(r.x, fr); dec4(r.y, fr + 4);
          const float* u0 = &uvf[l8 * 8];       const float* t0 = &tgtE[l8 * 8];
          const float* u1 = &uvf[64 + l8 * 8];  const float* t1 = &tgtE[64 + l8 * 8];
          float s1a = fe[0] * u0[0] + fe[1] * u0[1] + fe[2] * u0[2] + fe[3] * u0[3]
                    + fe[4] * u0[4] + fe[5] * u0[5] + fe[6] * u0[6] + fe[7] * u0[7]
                    + fr[0] * u1[0] + fr[1] * u1[1] + fr[2] * u1[2] + fr[3] * u1[3]
                    + fr[4] * u1[4] + fr[5] * u1[5] + fr[6] * u1[6] + fr[7] * u1[7];
          float s2a = fe[0] * t0[0] + fe[1] * t0[1] + fe[2] * t0[2] + fe[3] * t0[3]
                    + fe[4] * t0[4] + fe[5] * t0[5] + fe[6] * t0[6] + fe[7] * t0[7]
                    + fr[0] * t1[0] + fr[1] * t1[1] + fr[2] * t1[2] + fr[3] * t1[3]
                    + fr[4] * t1[4] + fr[5] * t1[5] + fr[6] * t1[6] + fr[7] * t1[7];
          s1a += __shfl_xor(s1a, 1, 64); s2a += __shfl_xor(s2a, 1, 64);
          s1a += __shfl_xor(s1a, 2, 64); s2a += __shfl_xor(s2a, 2, 64);
          s1a += __shfl_xor(s1a, 4, 64); s2a += __shfl_xor(s2a, 4, 64);
          if (l8 == 0) s12[(size_t)i * Hn + CR * h + t] = make_float2(s1a, s2a);
        }
      }

      // scores: buffer halfword index a'*200 + c (zero address math)
      if (tid < Hn) {
        float acc = 0.f;
        const USH* kp = &kvs[tid];
#pragma unroll
        for (int a = 0; a < 32; a++) acc += qv[a] * bf2f(kp[a * 200]);
        psc[((size_t)i * 4 + h) * Hn + tid] = acc;
      }
    }
  }
  grid.sync();

  // ===================== Phase C: epilogue =====================
  {
    float* red = smem;   // 8 floats
    int lane = tid & 63, wave = tid >> 6;
    for (int i = blockIdx.x; i < Bn; i += gridDim.x) {
      __syncthreads();   // protect red[] reuse across virtual blocks
      int tgt_i = target[i];

      float ea = 0.f; float2 sv = make_float2(0.f, 0.f);
      if (tid < Hn) {
        const float* pp = psc + (size_t)i * 4 * Hn + tid;
        float s = (pp[0] + pp[Hn]) + (pp[2 * Hn] + pp[3 * Hn]);
        sv = s12[(size_t)i * Hn + tid];
        ea = (history[(size_t)i * Hn + tid] != tgt_i) ? __expf(s) : 0.f;
      }
      float wsum = ea;
      for (int off = 32; off > 0; off >>= 1) wsum += __shfl_down(wsum, off, 64);
      if (lane == 0) red[wave] = wsum;
      __syncthreads();
      float esum = red[0] + red[1] + red[2] + red[3];
      float inv = esum > 0.f ? 1.f / sqrtf(esum) : 0.f;  // exp_sum ** 0.5 (BETA)

      float part = 0.f;
      if (tid < Hn) {
        float gc = g[tid]; gc = gc > 0.f ? gc : 0.f;  // relu
        float dm = dist_mat[(size_t)i * Hn + tid];
        float geo = __expf(-dm / (gc + 1.f));
        part = (ea * inv + geo) * sv.x + hv[tid] * sv.y;
      }
      __syncthreads();  // protect red[] reuse
      for (int off = 32; off > 0; off >>= 1) part += __shfl_down(part, off, 64);
      if (lane == 0) red[wave] = part;
      __syncthreads();
      if (tid == 0) {
        float pred = red[0] + red[1] + red[2] + red[3];
        out[i] = 1.f / (1.f + __expf(-pred));
      }
    }
  }
}

extern "C" void kernel_launch(void* const* d_in, const int* in_sizes, int n_in,
                              void* d_out, int out_size, void* d_ws, size_t ws_size,
                              hipStream_t stream) {
  const int*   history = (const int*)d_in[0];
  const int*   target  = (const int*)d_in[1];
  const int*   hregion = (const int*)d_in[2];
  const int*   tregion = (const int*)d_in[3];
  const float* hv      = (const float*)d_in[4];
  const float* dist    = (const float*)d_in[5];
  const int*   uid     = (const int*)d_in[6];
  const float* Et      = (const float*)d_in[7];
  const float* Er      = (const float*)d_in[8];
  const float* Edist   = (const float*)d_in[9];
  const float* Wq      = (const float*)d_in[10];
  const float* Wk      = (const float*)d_in[11];
  const float* Wv      = (const float*)d_in[12];

  char* w = (char*)d_ws;
  float* g   = (float*)w;                            // 1KB slot
  UCH*   Cf  = (UCH*)(w + 1024);                     // 50000*192 B = 9.6MB
  UCH*   Df  = Cf + (size_t)NITEM * RS;              // 1000*192 B = 192KB
  float* qvt = (float*)(Df + (size_t)NREG * RS);     // 1024*128 f32 = 512KB
  float* uvt = qvt + (size_t)Bn * Dn;                // 512KB
  float* psc = uvt + (size_t)Bn * Dn;                // 1024*4*200 f32 = 3.2MB
  float2* s12 = (float2*)(psc + (size_t)Bn * 4 * Hn);// 1024*200 float2 = 1.6MB
  float* out = (float*)d_out;

  hipMemsetAsync(g, 0, Hn * sizeof(float), stream);

  int maxb = 0;
  if (hipOccupancyMaxActiveBlocksPerMultiprocessor(&maxb, mega_kernel, 256, 0) != hipSuccess || maxb < 1)
    maxb = 3;   // LDS 51456B -> 3 blocks/CU expected
  int nblk = maxb * 256;
  if (nblk > 4096) nblk = 4096;

  void* args[] = {
      (void*)&history, (void*)&target, (void*)&hregion, (void*)&tregion,
      (void*)&hv, (void*)&dist, (void*)&uid,
      (void*)&Et, (void*)&Er, (void*)&Edist,
      (void*)&Wq, (void*)&Wk, (void*)&Wv,
      (void*)&Cf, (void*)&Df, (void*)&qvt, (void*)&uvt, (void*)&g,
      (void*)&psc, (void*)&s12, (void*)&out};
  hipLaunchCooperativeKernel(reinterpret_cast<const void*>(mega_kernel),
                             dim3(nblk), dim3(256), args, 0, stream);
}

// Round 7
// 150.922 us; speedup vs baseline: 1.9321x; 1.9321x over previous
//
#include <hip/hip_runtime.h>

typedef unsigned short USH;
typedef unsigned int   UIN;
typedef unsigned char  UCH;

static constexpr int Bn = 1024;    // batch
static constexpr int Hn = 200;     // history length
static constexpr int Dn = 128;     // embed/hidden
static constexpr int Dh = 64;      // half embed
static constexpr int NITEM = 50000;
static constexpr int NREG  = 1000;
static constexpr int MT = 64;      // items per ab block
static constexpr int AB_A_BLOCKS = (NITEM + MT - 1) / MT;  // 782
static constexpr int AB_B_BLOCKS = (NREG  + MT - 1) / MT;  // 16
static constexpr int AB_TOT = AB_A_BLOCKS + AB_B_BLOCKS;   // 798
static constexpr int QU_BLOCKS = Bn / 4;                   // 256 (4 rows/block)
static constexpr int G_BLOCKS  = Bn / 16;                  // 64  (16 rows/block)
static constexpr int WTS = 132;    // wt stride (floats)
static constexpr int ETS = 69;     // et stride (floats)
static constexpr int CR  = 50;     // kv rows per chunk (32*200 == 50*128)
static constexpr int RS  = 192;    // fused fp8 row stride: 128 proj + 64 raw

// fp8 tables scaled by FSCALE before encode; consumers fold in 1/FSCALE.
static constexpr float FSCALE = 128.f;
static constexpr float FINV   = 1.f / 128.f;

__device__ __forceinline__ float bf2f(USH u) {
  return __uint_as_float(((UIN)u) << 16);
}
__device__ __forceinline__ USH f2b(float f) {  // fp32 -> bf16 rne
  UIN x = __float_as_uint(f);
  return (USH)((x + 0x7fffu + ((x >> 16) & 1u)) >> 16);
}
__device__ __forceinline__ UIN enc4(float a, float b, float c, float d) {
  // 4 fp32 -> 4 fp8 e4m3 packed in one dword (hw cvt, RNE+sat)
  int w = __builtin_amdgcn_cvt_pk_fp8_f32(a, b, 0, false);
  w = __builtin_amdgcn_cvt_pk_fp8_f32(c, d, w, true);
  return (UIN)w;
}
__device__ __forceinline__ void dec4(UIN w, float* o) {  // 4 fp8 -> 4 fp32
  auto lo = __builtin_amdgcn_cvt_pk_f32_fp8((int)w, false);
  auto hi = __builtin_amdgcn_cvt_pk_f32_fp8((int)w, true);
  o[0] = lo[0]; o[1] = lo[1]; o[2] = hi[0]; o[3] = hi[1];
}

// ---------------------------------------------------------------------------
// ab_kernel (unchanged v15) grid = [table GEMM | qv/uv precompute | g accum]
// ---------------------------------------------------------------------------
__global__ __launch_bounds__(256, 2) void ab_kernel(
    const float* __restrict__ Et, const float* __restrict__ Er,
    const float* __restrict__ Wk, const float* __restrict__ Wq,
    const float* __restrict__ Wv, const int* __restrict__ target,
    const int* __restrict__ tregion, const int* __restrict__ hregion,
    const float* __restrict__ embed_dist, const int* __restrict__ uid,
    UCH* __restrict__ Cf, UCH* __restrict__ Df,
    float* __restrict__ qvt, float* __restrict__ uvt, float* __restrict__ g) {
  __shared__ float wt[64 * WTS];  // 33.8KB (qu path reuses as te[4][128])
  __shared__ float et[MT * ETS];  // 17.7KB
  int blk = blockIdx.x, tid = threadIdx.x;

  if (blk >= AB_TOT + QU_BLOCKS) {
    // ---------------- g-accumulate path (64 blocks x 16 rows) ----------------
    int c = tid;
    const float* row = embed_dist + (size_t)uid[0] * NREG;  // 4KB, L1-resident
    float acc = 0.f;
    int ibase = (blk - AB_TOT - QU_BLOCKS) * 16;
    for (int ii = 0; ii < 16; ii++) {
      int i = ibase + ii;
      float td = row[tregion[i]];             // wave-uniform broadcast
      if (c < Hn) acc += td * row[hregion[(size_t)i * Hn + c]];
    }
    if (c < Hn) atomicAdd(&g[c], acc);
    return;
  }

  if (blk >= AB_TOT) {
    // ---------------- qv/uv precompute path ----------------
    float* te = wt;  // te[ii*128 + d], 4 target-embed rows
    int i0 = (blk - AB_TOT) * 4;
#pragma unroll
    for (int v = 0; v < 2; v++) {
      int idx = v * 256 + tid;      // 0..511
      int ii = idx >> 7, d = idx & 127;
      int it = i0 + ii;
      te[ii * 128 + d] = (d < 64) ? Et[(size_t)target[it] * Dh + d]
                                  : Er[(size_t)tregion[it] * Dh + (d - 64)];
    }
    __syncthreads();
    int j = tid & 127, half = tid >> 7;
    float a0 = 0.f, a1 = 0.f, a2 = 0.f, a3 = 0.f;
    if (half == 0) {  // qv: thread j owns Wq row j, 4 batch rows at once
      const float* wr = Wq + (size_t)j * Dn;
#pragma unroll 8
      for (int k = 0; k < 128; k++) {
        float w = wr[k];
        a0 += w * te[k]; a1 += w * te[128 + k];
        a2 += w * te[256 + k]; a3 += w * te[384 + k];
      }
      const float s = 0.088388347648318447f;  // 1/sqrt(128)
      qvt[(size_t)(i0 + 0) * Dn + j] = a0 * s;
      qvt[(size_t)(i0 + 1) * Dn + j] = a1 * s;
      qvt[(size_t)(i0 + 2) * Dn + j] = a2 * s;
      qvt[(size_t)(i0 + 3) * Dn + j] = a3 * s;
    } else {          // uv: column sweep, coalesced across d
      int d = j;
#pragma unroll 8
      for (int k = 0; k < 128; k++) {
        float w = Wv[(size_t)k * Dn + d];
        a0 += w * te[k]; a1 += w * te[128 + k];
        a2 += w * te[256 + k]; a3 += w * te[384 + k];
      }
      uvt[(size_t)(i0 + 0) * Dn + d] = a0;
      uvt[(size_t)(i0 + 1) * Dn + d] = a1;
      uvt[(size_t)(i0 + 2) * Dn + d] = a2;
      uvt[(size_t)(i0 + 3) * Dn + d] = a3;
    }
    return;
  }

  // ---------------- fused-table GEMM path ----------------
  const float* E; UCH* OutT; int nmax, base, koff;
  if (blk < AB_A_BLOCKS) { E = Et; OutT = Cf; nmax = NITEM; base = blk * MT; koff = 0; }
  else { E = Er; OutT = Df; nmax = NREG; base = (blk - AB_A_BLOCKS) * MT; koff = 64; }

  // stage Wk transposed
#pragma unroll
  for (int p = 0; p < 8; p++) {
    int idx = p * 256 + tid;
    int row = idx >> 4, c4 = idx & 15;
    float4 w = *reinterpret_cast<const float4*>(Wk + (size_t)row * Dn + koff + c4 * 4);
    wt[(c4 * 4 + 0) * WTS + row] = w.x;
    wt[(c4 * 4 + 1) * WTS + row] = w.y;
    wt[(c4 * 4 + 2) * WTS + row] = w.z;
    wt[(c4 * 4 + 3) * WTS + row] = w.w;
  }
  // stage E rows row-major
#pragma unroll
  for (int p = 0; p < 4; p++) {
    int idx = p * 256 + tid;
    int m = idx >> 4, c4 = idx & 15;
    int gi = base + m;
    float4 e = make_float4(0.f, 0.f, 0.f, 0.f);
    if (gi < nmax) e = *reinterpret_cast<const float4*>(E + (size_t)gi * Dh + c4 * 4);
    et[m * ETS + c4 * 4 + 0] = e.x;
    et[m * ETS + c4 * 4 + 1] = e.y;
    et[m * ETS + c4 * 4 + 2] = e.z;
    et[m * ETS + c4 * 4 + 3] = e.w;
  }
  __syncthreads();

  // raw-half emit: Cf[item][128 + 4wr..] = fp8(FSCALE * E row)
#pragma unroll
  for (int p = 0; p < 4; p++) {
    int idx = p * 256 + tid;       // 0..1023
    int m = idx >> 4, wr = idx & 15;
    int gi = base + m;
    if (gi < nmax) {
      const float* er = &et[m * ETS + wr * 4];
      *reinterpret_cast<UIN*>(OutT + (size_t)gi * RS + 128 + wr * 4) =
          enc4(er[0] * FSCALE, er[1] * FSCALE, er[2] * FSCALE, er[3] * FSCALE);
    }
  }

  int jt = tid & 15, it = tid >> 4;     // 8 j's, 4 items per thread
  const float* wb = wt + jt * 8;
  const float* eb = et + (it * 4) * ETS;
  float c[4][8];
#pragma unroll
  for (int ii = 0; ii < 4; ii++)
#pragma unroll
    for (int jj = 0; jj < 8; jj++) c[ii][jj] = 0.f;

#pragma unroll 2
  for (int k = 0; k < 64; k++) {
    float4 w0 = *reinterpret_cast<const float4*>(wb + (size_t)k * WTS);
    float4 w1 = *reinterpret_cast<const float4*>(wb + (size_t)k * WTS + 4);
    float e0 = eb[k], e1 = eb[ETS + k], e2 = eb[2 * ETS + k], e3 = eb[3 * ETS + k];
    c[0][0] += e0 * w0.x; c[0][1] += e0 * w0.y; c[0][2] += e0 * w0.z; c[0][3] += e0 * w0.w;
    c[0][4] += e0 * w1.x; c[0][5] += e0 * w1.y; c[0][6] += e0 * w1.z; c[0][7] += e0 * w1.w;
    c[1][0] += e1 * w0.x; c[1][1] += e1 * w0.y; c[1][2] += e1 * w0.z; c[1][3] += e1 * w0.w;
    c[1][4] += e1 * w1.x; c[1][5] += e1 * w1.y; c[1][6] += e1 * w1.z; c[1][7] += e1 * w1.w;
    c[2][0] += e2 * w0.x; c[2][1] += e2 * w0.y; c[2][2] += e2 * w0.z; c[2][3] += e2 * w0.w;
    c[2][4] += e2 * w1.x; c[2][5] += e2 * w1.y; c[2][6] += e2 * w1.z; c[2][7] += e2 * w1.w;
    c[3][0] += e3 * w0.x; c[3][1] += e3 * w0.y; c[3][2] += e3 * w0.z; c[3][3] += e3 * w0.w;
    c[3][4] += e3 * w1.x; c[3][5] += e3 * w1.y; c[3][6] += e3 * w1.z; c[3][7] += e3 * w1.w;
  }

#pragma unroll
  for (int ii = 0; ii < 4; ii++) {
    int item = base + it * 4 + ii;
    if (item < nmax) {
      uint2 pk;
      pk.x = enc4(c[ii][0] * FSCALE, c[ii][1] * FSCALE, c[ii][2] * FSCALE, c[ii][3] * FSCALE);
      pk.y = enc4(c[ii][4] * FSCALE, c[ii][5] * FSCALE, c[ii][6] * FSCALE, c[ii][7] * FSCALE);
      *reinterpret_cast<uint2*>(OutT + (size_t)item * RS + jt * 8) = pk;
    }
  }
}

// ---------------------------------------------------------------------------
// v17: scep_kernel = sc + ep fused, ONE block per batch row (1024 blocks).
// 4 sequential 50-row chunks {stage -> barrier -> dots/psc -> barrier},
// psc accumulated in LDS (pacc), s12 kept in LDS, epilogue in-block.
// Removes ep launch+gap and 9.6MB psc/s12 global round-trip.
// LDS 22.8KB -> 7 blocks/CU; all 4 blocks/CU of work co-resident -> MLP kept.
// ---------------------------------------------------------------------------
__global__ __launch_bounds__(256, 4) void scep_kernel(
    const int* __restrict__ history, const int* __restrict__ target,
    const int* __restrict__ hregion, const int* __restrict__ tregion,
    const float* __restrict__ Et, const float* __restrict__ Er,
    const float* __restrict__ qvt, const float* __restrict__ uvt,
    const UCH* __restrict__ Cf, const UCH* __restrict__ Df,
    const float* __restrict__ hv, const float* __restrict__ dist_mat,
    const float* __restrict__ g, float* __restrict__ out) {
  __shared__ USH kvs[CR * Dn];        // 12800B bf16 proj sum (x FSCALE)
  __shared__ uint4 rawA[CR * 4];      // 3200B fp8 item raw rows
  __shared__ uint4 rawB[CR * 4];      // 3200B fp8 region raw rows
  __shared__ float tgtE[128], uvf[128], qv[32];
  __shared__ float pacc[Hn];          // score accumulator across chunks
  __shared__ float2 s12L[Hn];         // per-row s1/s2
  __shared__ float red[8];
  int i = blockIdx.x, tid = threadIdx.x;
  int tgt_i = target[i];

  for (int h = 0; h < 4; h++) {
    const int* hrow = history + (size_t)i * Hn + CR * h;
    const int* rrow = hregion + (size_t)i * Hn + CR * h;

    if (h == 0) {
      if (tid < 128) {
        tgtE[tid] = FINV * ((tid < 64) ? Et[(size_t)tgt_i * Dh + tid]
                                       : Er[(size_t)tregion[i] * Dh + (tid - 64)]);
      } else {
        uvf[tid - 128] = FINV * uvt[(size_t)i * Dn + (tid - 128)];
      }
      if (tid < Hn) pacc[tid] = 0.f;
    }
    if (tid < 32) qv[tid] = FINV * qvt[(size_t)i * Dn + 32 * h + tid];

    // raw staging: 4 lanes x 16B per row (200 active threads)
    {
      int seg = tid & 3, row = tid >> 2;
      if (row < CR) {
        int ia = hrow[row], ib = rrow[row];
        rawA[row * 4 + seg] = *reinterpret_cast<const uint4*>(Cf + (size_t)ia * RS + 128 + seg * 16);
        rawB[row * 4 + seg] = *reinterpret_cast<const uint4*>(Df + (size_t)ib * RS + 128 + seg * 16);
      }
    }

    // proj staging: 8 lanes x 16B per row; decode fp8, add, pack bf16
#pragma unroll
    for (int p = 0; p < 2; p++) {
      int idx = p * 256 + tid;
      int seg = idx & 7, row = idx >> 3;
      if (row < CR) {
        int ia = hrow[row], ib = rrow[row];
        uint4 av = *reinterpret_cast<const uint4*>(Cf + (size_t)ia * RS + seg * 16);
        uint4 bv = *reinterpret_cast<const uint4*>(Df + (size_t)ib * RS + seg * 16);
        float fa[16], fb[16];
        dec4(av.x, fa);      dec4(av.y, fa + 4);  dec4(av.z, fa + 8);  dec4(av.w, fa + 12);
        dec4(bv.x, fb);      dec4(bv.y, fb + 4);  dec4(bv.z, fb + 8);  dec4(bv.w, fb + 12);
        uint4 k0, k1;
        k0.x = (UIN)f2b(fa[0] + fb[0])  | ((UIN)f2b(fa[1] + fb[1]) << 16);
        k0.y = (UIN)f2b(fa[2] + fb[2])  | ((UIN)f2b(fa[3] + fb[3]) << 16);
        k0.z = (UIN)f2b(fa[4] + fb[4])  | ((UIN)f2b(fa[5] + fb[5]) << 16);
        k0.w = (UIN)f2b(fa[6] + fb[6])  | ((UIN)f2b(fa[7] + fb[7]) << 16);
        k1.x = (UIN)f2b(fa[8] + fb[8])  | ((UIN)f2b(fa[9] + fb[9]) << 16);
        k1.y = (UIN)f2b(fa[10] + fb[10]) | ((UIN)f2b(fa[11] + fb[11]) << 16);
        k1.z = (UIN)f2b(fa[12] + fb[12]) | ((UIN)f2b(fa[13] + fb[13]) << 16);
        k1.w = (UIN)f2b(fa[14] + fb[14]) | ((UIN)f2b(fa[15] + fb[15]) << 16);
        *reinterpret_cast<uint4*>(&kvs[row * Dn + seg * 16]) = k0;
        *reinterpret_cast<uint4*>(&kvs[row * Dn + seg * 16 + 8]) = k1;
      }
    }
    __syncthreads();  // staged chunk + (h==0: pacc/tgtE/uvf) ready

    // s1/s2 dots from LDS raw fp8 -> s12L
    int l8 = tid & 7, r8 = tid >> 3;     // 8 lanes/row; rows r8 and 32+r8
#pragma unroll
    for (int pass = 0; pass < 2; pass++) {
      int t = (pass == 0) ? r8 : 32 + r8;
      if (t < CR) {
        uint2 e = *(reinterpret_cast<const uint2*>(&rawA[t * 4]) + l8);
        uint2 r = *(reinterpret_cast<const uint2*>(&rawB[t * 4]) + l8);
        float fe[8], fr[8];
        dec4(e.x, fe); dec4(e.y, fe + 4);
        dec4(r.x, fr); dec4(r.y, fr + 4);
        const float* u0 = &uvf[l8 * 8];       const float* t0 = &tgtE[l8 * 8];
        const float* u1 = &uvf[64 + l8 * 8];  const float* t1 = &tgtE[64 + l8 * 8];
        float s1a = fe[0] * u0[0] + fe[1] * u0[1] + fe[2] * u0[2] + fe[3] * u0[3]
                  + fe[4] * u0[4] + fe[5] * u0[5] + fe[6] * u0[6] + fe[7] * u0[7]
                  + fr[0] * u1[0] + fr[1] * u1[1] + fr[2] * u1[2] + fr[3] * u1[3]
                  + fr[4] * u1[4] + fr[5] * u1[5] + fr[6] * u1[6] + fr[7] * u1[7];
        float s2a = fe[0] * t0[0] + fe[1] * t0[1] + fe[2] * t0[2] + fe[3] * t0[3]
                  + fe[4] * t0[4] + fe[5] * t0[5] + fe[6] * t0[6] + fe[7] * t0[7]
                  + fr[0] * t1[0] + fr[1] * t1[1] + fr[2] * t1[2] + fr[3] * t1[3]
                  + fr[4] * t1[4] + fr[5] * t1[5] + fr[6] * t1[6] + fr[7] * t1[7];
        s1a += __shfl_xor(s1a, 1, 64); s2a += __shfl_xor(s2a, 1, 64);
        s1a += __shfl_xor(s1a, 2, 64); s2a += __shfl_xor(s2a, 2, 64);
        s1a += __shfl_xor(s1a, 4, 64); s2a += __shfl_xor(s2a, 4, 64);
        if (l8 == 0) s12L[CR * h + t] = make_float2(s1a, s2a);
      }
    }

    // partial score accumulate: linearized-k trick (a'*200 + c)
    if (tid < Hn) {
      float acc = 0.f;
      const USH* kp = &kvs[tid];
#pragma unroll
      for (int a = 0; a < 32; a++) acc += qv[a] * bf2f(kp[a * 200]);
      pacc[tid] += acc;
    }
    __syncthreads();  // chunk consumed; safe to restage next h
  }

  // ---------------- epilogue (from LDS) ----------------
  int lane = tid & 63, wave = tid >> 6;
  float ea = 0.f; float2 sv = make_float2(0.f, 0.f);
  if (tid < Hn) {
    sv = s12L[tid];
    ea = (history[(size_t)i * Hn + tid] != tgt_i) ? __expf(pacc[tid]) : 0.f;
  }
  float wsum = ea;
  for (int off = 32; off > 0; off >>= 1) wsum += __shfl_down(wsum, off, 64);
  if (lane == 0) red[wave] = wsum;
  __syncthreads();
  float esum = red[0] + red[1] + red[2] + red[3];
  float inv = esum > 0.f ? 1.f / sqrtf(esum) : 0.f;  // exp_sum ** 0.5 (BETA)

  float part = 0.f;
  if (tid < Hn) {
    float gc = g[tid]; gc = gc > 0.f ? gc : 0.f;  // relu
    float dm = dist_mat[(size_t)i * Hn + tid];
    float geo = __expf(-dm / (gc + 1.f));
    part = (ea * inv + geo) * sv.x + hv[tid] * sv.y;
  }
  __syncthreads();  // protect red[] reuse
  for (int off = 32; off > 0; off >>= 1) part += __shfl_down(part, off, 64);
  if (lane == 0) red[wave] = part;
  __syncthreads();
  if (tid == 0) {
    float pred = red[0] + red[1] + red[2] + red[3];
    out[i] = 1.f / (1.f + __expf(-pred));
  }
}

extern "C" void kernel_launch(void* const* d_in, const int* in_sizes, int n_in,
                              void* d_out, int out_size, void* d_ws, size_t ws_size,
                              hipStream_t stream) {
  const int*   history = (const int*)d_in[0];
  const int*   target  = (const int*)d_in[1];
  const int*   hregion = (const int*)d_in[2];
  const int*   tregion = (const int*)d_in[3];
  const float* hv      = (const float*)d_in[4];
  const float* dist    = (const float*)d_in[5];
  const int*   uid     = (const int*)d_in[6];
  const float* Et      = (const float*)d_in[7];
  const float* Er      = (const float*)d_in[8];
  const float* Edist   = (const float*)d_in[9];
  const float* Wq      = (const float*)d_in[10];
  const float* Wk      = (const float*)d_in[11];
  const float* Wv      = (const float*)d_in[12];

  char* w = (char*)d_ws;
  float* g   = (float*)w;                            // 1KB slot
  UCH*   Cf  = (UCH*)(w + 1024);                     // 50000*192 B = 9.6MB
  UCH*   Df  = Cf + (size_t)NITEM * RS;              // 1000*192 B = 192KB
  float* qvt = (float*)(Df + (size_t)NREG * RS);     // 1024*128 f32 = 512KB
  float* uvt = qvt + (size_t)Bn * Dn;                // 512KB
  float* out = (float*)d_out;

  hipMemsetAsync(g, 0, Hn * sizeof(float), stream);
  ab_kernel<<<AB_TOT + QU_BLOCKS + G_BLOCKS, 256, 0, stream>>>(
      Et, Er, Wk, Wq, Wv, target, tregion, hregion, Edist, uid,
      Cf, Df, qvt, uvt, g);
  scep_kernel<<<Bn, 256, 0, stream>>>(history, target, hregion, tregion,
                                      Et, Er, qvt, uvt, Cf, Df,
                                      hv, dist, g, out);
}

// Round 8
// 148.338 us; speedup vs baseline: 1.9658x; 1.0174x over previous
//
#include <hip/hip_runtime.h>

typedef unsigned short USH;
typedef unsigned int   UIN;
typedef unsigned char  UCH;

static constexpr int Bn = 1024;    // batch
static constexpr int Hn = 200;     // history length
static constexpr int Dn = 128;     // embed/hidden
static constexpr int Dh = 64;      // half embed
static constexpr int NITEM = 50000;
static constexpr int NREG  = 1000;
static constexpr int MT = 64;      // items per ab block
static constexpr int AB_A_BLOCKS = (NITEM + MT - 1) / MT;  // 782
static constexpr int AB_B_BLOCKS = (NREG  + MT - 1) / MT;  // 16
static constexpr int AB_TOT = AB_A_BLOCKS + AB_B_BLOCKS;   // 798
static constexpr int QU_BLOCKS = Bn / 4;                   // 256 (4 rows/block)
static constexpr int G_BLOCKS  = Bn / 16;                  // 64  (16 rows/block)
static constexpr int WTS = 136;    // wt stride (bf16 units; 272B rows, 16B-aligned)
static constexpr int ETS = 69;     // et stride (floats)
static constexpr int CR  = 50;     // kv rows per chunk (32*200 == 50*128)
static constexpr int RS  = 192;    // fused fp8 row stride: 128 proj + 64 raw

// fp8 tables scaled by FSCALE before encode; consumers fold in 1/FSCALE.
static constexpr float FSCALE = 128.f;
static constexpr float FINV   = 1.f / 128.f;

__device__ __forceinline__ float bf2f(USH u) {
  return __uint_as_float(((UIN)u) << 16);
}
__device__ __forceinline__ float2 pb2f2(UIN p) {  // packed bf16 pair -> 2 floats
  float2 r;
  r.x = __uint_as_float(p << 16);
  r.y = __uint_as_float(p & 0xffff0000u);
  return r;
}
__device__ __forceinline__ USH f2b(float f) {  // fp32 -> bf16 rne
  UIN x = __float_as_uint(f);
  return (USH)((x + 0x7fffu + ((x >> 16) & 1u)) >> 16);
}
__device__ __forceinline__ UIN enc4(float a, float b, float c, float d) {
  // 4 fp32 -> 4 fp8 e4m3 packed in one dword (hw cvt, RNE+sat)
  int w = __builtin_amdgcn_cvt_pk_fp8_f32(a, b, 0, false);
  w = __builtin_amdgcn_cvt_pk_fp8_f32(c, d, w, true);
  return (UIN)w;
}
__device__ __forceinline__ void dec4(UIN w, float* o) {  // 4 fp8 -> 4 fp32
  auto lo = __builtin_amdgcn_cvt_pk_f32_fp8((int)w, false);
  auto hi = __builtin_amdgcn_cvt_pk_f32_fp8((int)w, true);
  o[0] = lo[0]; o[1] = lo[1]; o[2] = hi[0]; o[3] = hi[1];
}

// ---------------------------------------------------------------------------
// ab_kernel v18: Wk tile staged as bf16 (17.4KB) -> total LDS 35.1KB ->
// 4 blocks/CU (was 2). MAC loop reads 8 bf16 weights per uint4, decodes via
// shifts; accumulation stays f32. Output fp8 quantization dominates the
// added bf16 weight error. qv/uv path reuses wt space as f32 te (8KB < 17.4).
// ---------------------------------------------------------------------------
__global__ __launch_bounds__(256, 4) void ab_kernel(
    const float* __restrict__ Et, const float* __restrict__ Er,
    const float* __restrict__ Wk, const float* __restrict__ Wq,
    const float* __restrict__ Wv, const int* __restrict__ target,
    const int* __restrict__ tregion, const int* __restrict__ hregion,
    const float* __restrict__ embed_dist, const int* __restrict__ uid,
    UCH* __restrict__ Cf, UCH* __restrict__ Df,
    float* __restrict__ qvt, float* __restrict__ uvt, float* __restrict__ g) {
  __shared__ USH  wtu[64 * WTS];  // 17408B bf16 Wk^T tile (qu path: te[4][128] f32)
  __shared__ float et[MT * ETS];  // 17664B
  int blk = blockIdx.x, tid = threadIdx.x;

  if (blk >= AB_TOT + QU_BLOCKS) {
    // ---------------- g-accumulate path (64 blocks x 16 rows) ----------------
    int c = tid;
    const float* row = embed_dist + (size_t)uid[0] * NREG;  // 4KB, L1-resident
    float acc = 0.f;
    int ibase = (blk - AB_TOT - QU_BLOCKS) * 16;
    for (int ii = 0; ii < 16; ii++) {
      int i = ibase + ii;
      float td = row[tregion[i]];             // wave-uniform broadcast
      if (c < Hn) acc += td * row[hregion[(size_t)i * Hn + c]];
    }
    if (c < Hn) atomicAdd(&g[c], acc);
    return;
  }

  if (blk >= AB_TOT) {
    // ---------------- qv/uv precompute path ----------------
    float* te = reinterpret_cast<float*>(wtu);  // te[ii*128 + d], 4 rows (8KB)
    int i0 = (blk - AB_TOT) * 4;
#pragma unroll
    for (int v = 0; v < 2; v++) {
      int idx = v * 256 + tid;      // 0..511
      int ii = idx >> 7, d = idx & 127;
      int it = i0 + ii;
      te[ii * 128 + d] = (d < 64) ? Et[(size_t)target[it] * Dh + d]
                                  : Er[(size_t)tregion[it] * Dh + (d - 64)];
    }
    __syncthreads();
    int j = tid & 127, half = tid >> 7;
    float a0 = 0.f, a1 = 0.f, a2 = 0.f, a3 = 0.f;
    if (half == 0) {  // qv: thread j owns Wq row j, 4 batch rows at once
      const float* wr = Wq + (size_t)j * Dn;
#pragma unroll 8
      for (int k = 0; k < 128; k++) {
        float w = wr[k];
        a0 += w * te[k]; a1 += w * te[128 + k];
        a2 += w * te[256 + k]; a3 += w * te[384 + k];
      }
      const float s = 0.088388347648318447f;  // 1/sqrt(128)
      qvt[(size_t)(i0 + 0) * Dn + j] = a0 * s;
      qvt[(size_t)(i0 + 1) * Dn + j] = a1 * s;
      qvt[(size_t)(i0 + 2) * Dn + j] = a2 * s;
      qvt[(size_t)(i0 + 3) * Dn + j] = a3 * s;
    } else {          // uv: column sweep, coalesced across d
      int d = j;
#pragma unroll 8
      for (int k = 0; k < 128; k++) {
        float w = Wv[(size_t)k * Dn + d];
        a0 += w * te[k]; a1 += w * te[128 + k];
        a2 += w * te[256 + k]; a3 += w * te[384 + k];
      }
      uvt[(size_t)(i0 + 0) * Dn + d] = a0;
      uvt[(size_t)(i0 + 1) * Dn + d] = a1;
      uvt[(size_t)(i0 + 2) * Dn + d] = a2;
      uvt[(size_t)(i0 + 3) * Dn + d] = a3;
    }
    return;
  }

  // ---------------- fused-table GEMM path ----------------
  const float* E; UCH* OutT; int nmax, base, koff;
  if (blk < AB_A_BLOCKS) { E = Et; OutT = Cf; nmax = NITEM; base = blk * MT; koff = 0; }
  else { E = Er; OutT = Df; nmax = NREG; base = (blk - AB_A_BLOCKS) * MT; koff = 64; }

  // stage Wk transposed as bf16
#pragma unroll
  for (int p = 0; p < 8; p++) {
    int idx = p * 256 + tid;
    int row = idx >> 4, c4 = idx & 15;
    float4 w = *reinterpret_cast<const float4*>(Wk + (size_t)row * Dn + koff + c4 * 4);
    wtu[(c4 * 4 + 0) * WTS + row] = f2b(w.x);
    wtu[(c4 * 4 + 1) * WTS + row] = f2b(w.y);
    wtu[(c4 * 4 + 2) * WTS + row] = f2b(w.z);
    wtu[(c4 * 4 + 3) * WTS + row] = f2b(w.w);
  }
  // stage E rows row-major
#pragma unroll
  for (int p = 0; p < 4; p++) {
    int idx = p * 256 + tid;
    int m = idx >> 4, c4 = idx & 15;
    int gi = base + m;
    float4 e = make_float4(0.f, 0.f, 0.f, 0.f);
    if (gi < nmax) e = *reinterpret_cast<const float4*>(E + (size_t)gi * Dh + c4 * 4);
    et[m * ETS + c4 * 4 + 0] = e.x;
    et[m * ETS + c4 * 4 + 1] = e.y;
    et[m * ETS + c4 * 4 + 2] = e.z;
    et[m * ETS + c4 * 4 + 3] = e.w;
  }
  __syncthreads();

  // raw-half emit: Cf[item][128 + 4wr..] = fp8(FSCALE * E row)
#pragma unroll
  for (int p = 0; p < 4; p++) {
    int idx = p * 256 + tid;       // 0..1023
    int m = idx >> 4, wr = idx & 15;
    int gi = base + m;
    if (gi < nmax) {
      const float* er = &et[m * ETS + wr * 4];
      *reinterpret_cast<UIN*>(OutT + (size_t)gi * RS + 128 + wr * 4) =
          enc4(er[0] * FSCALE, er[1] * FSCALE, er[2] * FSCALE, er[3] * FSCALE);
    }
  }

  int jt = tid & 15, it = tid >> 4;     // 8 j's, 4 items per thread
  const USH* wb = wtu + jt * 8;
  const float* eb = et + (it * 4) * ETS;
  float c[4][8];
#pragma unroll
  for (int ii = 0; ii < 4; ii++)
#pragma unroll
    for (int jj = 0; jj < 8; jj++) c[ii][jj] = 0.f;

#pragma unroll 2
  for (int k = 0; k < 64; k++) {
    uint4 wv = *reinterpret_cast<const uint4*>(wb + (size_t)k * WTS);  // 8 bf16, 16B-aligned
    float2 wp0 = pb2f2(wv.x), wp1 = pb2f2(wv.y), wp2 = pb2f2(wv.z), wp3 = pb2f2(wv.w);
    float e0 = eb[k], e1 = eb[ETS + k], e2 = eb[2 * ETS + k], e3 = eb[3 * ETS + k];
    c[0][0] += e0 * wp0.x; c[0][1] += e0 * wp0.y; c[0][2] += e0 * wp1.x; c[0][3] += e0 * wp1.y;
    c[0][4] += e0 * wp2.x; c[0][5] += e0 * wp2.y; c[0][6] += e0 * wp3.x; c[0][7] += e0 * wp3.y;
    c[1][0] += e1 * wp0.x; c[1][1] += e1 * wp0.y; c[1][2] += e1 * wp1.x; c[1][3] += e1 * wp1.y;
    c[1][4] += e1 * wp2.x; c[1][5] += e1 * wp2.y; c[1][6] += e1 * wp3.x; c[1][7] += e1 * wp3.y;
    c[2][0] += e2 * wp0.x; c[2][1] += e2 * wp0.y; c[2][2] += e2 * wp1.x; c[2][3] += e2 * wp1.y;
    c[2][4] += e2 * wp2.x; c[2][5] += e2 * wp2.y; c[2][6] += e2 * wp3.x; c[2][7] += e2 * wp3.y;
    c[3][0] += e3 * wp0.x; c[3][1] += e3 * wp0.y; c[3][2] += e3 * wp1.x; c[3][3] += e3 * wp1.y;
    c[3][4] += e3 * wp2.x; c[3][5] += e3 * wp2.y; c[3][6] += e3 * wp3.x; c[3][7] += e3 * wp3.y;
  }

#pragma unroll
  for (int ii = 0; ii < 4; ii++) {
    int item = base + it * 4 + ii;
    if (item < nmax) {
      uint2 pk;
      pk.x = enc4(c[ii][0] * FSCALE, c[ii][1] * FSCALE, c[ii][2] * FSCALE, c[ii][3] * FSCALE);
      pk.y = enc4(c[ii][4] * FSCALE, c[ii][5] * FSCALE, c[ii][6] * FSCALE, c[ii][7] * FSCALE);
      *reinterpret_cast<uint2*>(OutT + (size_t)item * RS + jt * 8) = pk;
    }
  }
}

// ---------------------------------------------------------------------------
// scep_kernel (unchanged v17): sc + ep fused, one block per batch row.
// ---------------------------------------------------------------------------
__global__ __launch_bounds__(256, 4) void scep_kernel(
    const int* __restrict__ history, const int* __restrict__ target,
    const int* __restrict__ hregion, const int* __restrict__ tregion,
    const float* __restrict__ Et, const float* __restrict__ Er,
    const float* __restrict__ qvt, const float* __restrict__ uvt,
    const UCH* __restrict__ Cf, const UCH* __restrict__ Df,
    const float* __restrict__ hv, const float* __restrict__ dist_mat,
    const float* __restrict__ g, float* __restrict__ out) {
  __shared__ USH kvs[CR * Dn];        // 12800B bf16 proj sum (x FSCALE)
  __shared__ uint4 rawA[CR * 4];      // 3200B fp8 item raw rows
  __shared__ uint4 rawB[CR * 4];      // 3200B fp8 region raw rows
  __shared__ float tgtE[128], uvf[128], qv[32];
  __shared__ float pacc[Hn];          // score accumulator across chunks
  __shared__ float2 s12L[Hn];         // per-row s1/s2
  __shared__ float red[8];
  int i = blockIdx.x, tid = threadIdx.x;
  int tgt_i = target[i];

  for (int h = 0; h < 4; h++) {
    const int* hrow = history + (size_t)i * Hn + CR * h;
    const int* rrow = hregion + (size_t)i * Hn + CR * h;

    if (h == 0) {
      if (tid < 128) {
        tgtE[tid] = FINV * ((tid < 64) ? Et[(size_t)tgt_i * Dh + tid]
                                       : Er[(size_t)tregion[i] * Dh + (tid - 64)]);
      } else {
        uvf[tid - 128] = FINV * uvt[(size_t)i * Dn + (tid - 128)];
      }
      if (tid < Hn) pacc[tid] = 0.f;
    }
    if (tid < 32) qv[tid] = FINV * qvt[(size_t)i * Dn + 32 * h + tid];

    // raw staging: 4 lanes x 16B per row (200 active threads)
    {
      int seg = tid & 3, row = tid >> 2;
      if (row < CR) {
        int ia = hrow[row], ib = rrow[row];
        rawA[row * 4 + seg] = *reinterpret_cast<const uint4*>(Cf + (size_t)ia * RS + 128 + seg * 16);
        rawB[row * 4 + seg] = *reinterpret_cast<const uint4*>(Df + (size_t)ib * RS + 128 + seg * 16);
      }
    }

    // proj staging: 8 lanes x 16B per row; decode fp8, add, pack bf16
#pragma unroll
    for (int p = 0; p < 2; p++) {
      int idx = p * 256 + tid;
      int seg = idx & 7, row = idx >> 3;
      if (row < CR) {
        int ia = hrow[row], ib = rrow[row];
        uint4 av = *reinterpret_cast<const uint4*>(Cf + (size_t)ia * RS + seg * 16);
        uint4 bv = *reinterpret_cast<const uint4*>(Df + (size_t)ib * RS + seg * 16);
        float fa[16], fb[16];
        dec4(av.x, fa);      dec4(av.y, fa + 4);  dec4(av.z, fa + 8);  dec4(av.w, fa + 12);
        dec4(bv.x, fb);      dec4(bv.y, fb + 4);  dec4(bv.z, fb + 8);  dec4(bv.w, fb + 12);
        uint4 k0, k1;
        k0.x = (UIN)f2b(fa[0] + fb[0])  | ((UIN)f2b(fa[1] + fb[1]) << 16);
        k0.y = (UIN)f2b(fa[2] + fb[2])  | ((UIN)f2b(fa[3] + fb[3]) << 16);
        k0.z = (UIN)f2b(fa[4] + fb[4])  | ((UIN)f2b(fa[5] + fb[5]) << 16);
        k0.w = (UIN)f2b(fa[6] + fb[6])  | ((UIN)f2b(fa[7] + fb[7]) << 16);
        k1.x = (UIN)f2b(fa[8] + fb[8])  | ((UIN)f2b(fa[9] + fb[9]) << 16);
        k1.y = (UIN)f2b(fa[10] + fb[10]) | ((UIN)f2b(fa[11] + fb[11]) << 16);
        k1.z = (UIN)f2b(fa[12] + fb[12]) | ((UIN)f2b(fa[13] + fb[13]) << 16);
        k1.w = (UIN)f2b(fa[14] + fb[14]) | ((UIN)f2b(fa[15] + fb[15]) << 16);
        *reinterpret_cast<uint4*>(&kvs[row * Dn + seg * 16]) = k0;
        *reinterpret_cast<uint4*>(&kvs[row * Dn + seg * 16 + 8]) = k1;
      }
    }
    __syncthreads();  // staged chunk + (h==0: pacc/tgtE/uvf) ready

    // s1/s2 dots from LDS raw fp8 -> s12L
    int l8 = tid & 7, r8 = tid >> 3;     // 8 lanes/row; rows r8 and 32+r8
#pragma unroll
    for (int pass = 0; pass < 2; pass++) {
      int t = (pass == 0) ? r8 : 32 + r8;
      if (t < CR) {
        uint2 e = *(reinterpret_cast<const uint2*>(&rawA[t * 4]) + l8);
        uint2 r = *(reinterpret_cast<const uint2*>(&rawB[t * 4]) + l8);
        float fe[8], fr[8];
        dec4(e.x, fe); dec4(e.y, fe + 4);
        dec4(r.x, fr); dec4(r.y, fr + 4);
        const float* u0 = &uvf[l8 * 8];       const float* t0 = &tgtE[l8 * 8];
        const float* u1 = &uvf[64 + l8 * 8];  const float* t1 = &tgtE[64 + l8 * 8];
        float s1a = fe[0] * u0[0] + fe[1] * u0[1] + fe[2] * u0[2] + fe[3] * u0[3]
                  + fe[4] * u0[4] + fe[5] * u0[5] + fe[6] * u0[6] + fe[7] * u0[7]
                  + fr[0] * u1[0] + fr[1] * u1[1] + fr[2] * u1[2] + fr[3] * u1[3]
                  + fr[4] * u1[4] + fr[5] * u1[5] + fr[6] * u1[6] + fr[7] * u1[7];
        float s2a = fe[0] * t0[0] + fe[1] * t0[1] + fe[2] * t0[2] + fe[3] * t0[3]
                  + fe[4] * t0[4] + fe[5] * t0[5] + fe[6] * t0[6] + fe[7] * t0[7]
                  + fr[0] * t1[0] + fr[1] * t1[1] + fr[2] * t1[2] + fr[3] * t1[3]
                  + fr[4] * t1[4] + fr[5] * t1[5] + fr[6] * t1[6] + fr[7] * t1[7];
        s1a += __shfl_xor(s1a, 1, 64); s2a += __shfl_xor(s2a, 1, 64);
        s1a += __shfl_xor(s1a, 2, 64); s2a += __shfl_xor(s2a, 2, 64);
        s1a += __shfl_xor(s1a, 4, 64); s2a += __shfl_xor(s2a, 4, 64);
        if (l8 == 0) s12L[CR * h + t] = make_float2(s1a, s2a);
      }
    }

    // partial score accumulate: linearized-k trick (a'*200 + c)
    if (tid < Hn) {
      float acc = 0.f;
      const USH* kp = &kvs[tid];
#pragma unroll
      for (int a = 0; a < 32; a++) acc += qv[a] * bf2f(kp[a * 200]);
      pacc[tid] += acc;
    }
    __syncthreads();  // chunk consumed; safe to restage next h
  }

  // ---------------- epilogue (from LDS) ----------------
  int lane = tid & 63, wave = tid >> 6;
  float ea = 0.f; float2 sv = make_float2(0.f, 0.f);
  if (tid < Hn) {
    sv = s12L[tid];
    ea = (history[(size_t)i * Hn + tid] != tgt_i) ? __expf(pacc[tid]) : 0.f;
  }
  float wsum = ea;
  for (int off = 32; off > 0; off >>= 1) wsum += __shfl_down(wsum, off, 64);
  if (lane == 0) red[wave] = wsum;
  __syncthreads();
  float esum = red[0] + red[1] + red[2] + red[3];
  float inv = esum > 0.f ? 1.f / sqrtf(esum) : 0.f;  // exp_sum ** 0.5 (BETA)

  float part = 0.f;
  if (tid < Hn) {
    float gc = g[tid]; gc = gc > 0.f ? gc : 0.f;  // relu
    float dm = dist_mat[(size_t)i * Hn + tid];
    float geo = __expf(-dm / (gc + 1.f));
    part = (ea * inv + geo) * sv.x + hv[tid] * sv.y;
  }
  __syncthreads();  // protect red[] reuse
  for (int off = 32; off > 0; off >>= 1) part += __shfl_down(part, off, 64);
  if (lane == 0) red[wave] = part;
  __syncthreads();
  if (tid == 0) {
    float pred = red[0] + red[1] + red[2] + red[3];
    out[i] = 1.f / (1.f + __expf(-pred));
  }
}

extern "C" void kernel_launch(void* const* d_in, const int* in_sizes, int n_in,
                              void* d_out, int out_size, void* d_ws, size_t ws_size,
                              hipStream_t stream) {
  const int*   history = (const int*)d_in[0];
  const int*   target  = (const int*)d_in[1];
  const int*   hregion = (const int*)d_in[2];
  const int*   tregion = (const int*)d_in[3];
  const float* hv      = (const float*)d_in[4];
  const float* dist    = (const float*)d_in[5];
  const int*   uid     = (const int*)d_in[6];
  const float* Et      = (const float*)d_in[7];
  const float* Er      = (const float*)d_in[8];
  const float* Edist   = (const float*)d_in[9];
  const float* Wq      = (const float*)d_in[10];
  const float* Wk      = (const float*)d_in[11];
  const float* Wv      = (const float*)d_in[12];

  char* w = (char*)d_ws;
  float* g   = (float*)w;                            // 1KB slot
  UCH*   Cf  = (UCH*)(w + 1024);                     // 50000*192 B = 9.6MB
  UCH*   Df  = Cf + (size_t)NITEM * RS;              // 1000*192 B = 192KB
  float* qvt = (float*)(Df + (size_t)NREG * RS);     // 1024*128 f32 = 512KB
  float* uvt = qvt + (size_t)Bn * Dn;                // 512KB
  float* out = (float*)d_out;

  hipMemsetAsync(g, 0, Hn * sizeof(float), stream);
  ab_kernel<<<AB_TOT + QU_BLOCKS + G_BLOCKS, 256, 0, stream>>>(
      Et, Er, Wk, Wq, Wv, target, tregion, hregion, Edist, uid,
      Cf, Df, qvt, uvt, g);
  scep_kernel<<<Bn, 256, 0, stream>>>(history, target, hregion, tregion,
                                      Et, Er, qvt, uvt, Cf, Df,
                                      hv, dist, g, out);
}